// Round 6
// baseline (2214.492 us; speedup 1.0000x reference)
//
#include <hip/hip_runtime.h>
#include <cstdint>
#include <cstddef>

typedef __attribute__((ext_vector_type(8))) short bf16x8;
typedef bf16x8 __attribute__((may_alias)) bf16x8_a;
typedef __attribute__((ext_vector_type(4))) float f32x4;
typedef unsigned short u16;
typedef u16 __attribute__((may_alias)) u16_a;
typedef uint2 __attribute__((may_alias)) uint2_a;
typedef uint4 __attribute__((may_alias)) uint4_a;

#define LO_OFF 184320
#define MFMA16(a,b,c) __builtin_amdgcn_mfma_f32_16x16x32_bf16((a),(b),(c),0,0,0)
// Compiler-only ordering fence for LDS write->read phase boundaries.
#define LDS_FENCE() asm volatile("" ::: "memory")

__device__ __forceinline__ u16 f2bf(float f) {
  union { float f; unsigned u; } c; c.f = f;
  unsigned u = c.u + 0x7fffu + ((c.u >> 16) & 1u);
  return (u16)(u >> 16);
}
__device__ __forceinline__ float bf2f(u16 h) {
  union { unsigned u; float f; } c; c.u = ((unsigned)h) << 16;
  return c.f;
}
__device__ __forceinline__ void split4(float4 v, uint2& hw, uint2& lw) {
  u16 h0 = f2bf(v.x), h1 = f2bf(v.y), h2 = f2bf(v.z), h3 = f2bf(v.w);
  hw.x = (unsigned)h0 | ((unsigned)h1 << 16);
  hw.y = (unsigned)h2 | ((unsigned)h3 << 16);
  lw.x = (unsigned)f2bf(v.x - bf2f(h0)) | ((unsigned)f2bf(v.y - bf2f(h1)) << 16);
  lw.y = (unsigned)f2bf(v.z - bf2f(h2)) | ((unsigned)f2bf(v.w - bf2f(h3)) << 16);
}

// ---------------- weight prep: fp32 [K][128] -> frag-linear split-bf16 ----------------
// fragment fc = nt*KC + kc; elem (fc*64 + lane)*8 + j  <->  n = nt*16 + (lane&15),
// k = kc*32 + (lane>>4)*8 + j   (zero-padded past K)
struct PrepP {
  const float* w[9];
  u16* out;
};

__global__ __launch_bounds__(256) void prep_kernel(PrepP pp) {
  int gid = blockIdx.x * 256 + threadIdx.x;
  if (gid >= LO_OFF) return;
  const int Ks[9]  = {256,128,128, 256,128,128, 129,128,128};
  const int szs[9] = {32768,16384,16384, 32768,16384,16384, 20480,16384,16384};
  const int KCs[9] = {8,4,4, 8,4,4, 5,4,4};
  int m = 0, off = gid;
  while (m < 8 && off >= szs[m]) { off -= szs[m]; ++m; }
  int j    = off & 7;
  int t    = off >> 3;
  int lane = t & 63;
  int fc   = t >> 6;          // nt*KC + kc
  int KC   = KCs[m];
  int kc   = fc % KC;
  int nt   = fc / KC;
  int n = nt * 16 + (lane & 15);
  int k = kc * 32 + (lane >> 4) * 8 + j;
  float v = 0.f;
  if (k < Ks[m]) v = pp.w[m][(size_t)k * 128 + n];
  u16 hi = f2bf(v);
  u16 lo = f2bf(v - bf2f(hi));
  pp.out[gid] = hi;
  pp.out[LO_OFF + gid] = lo;
}

// ---------------- per-wave 16-row 3-layer MLP tile ----------------
struct WTP {
  const float* gA;     // mode0: x_in; mode1/2: xw
  const float* gB;     // mode0: edge_features
  const float* addb;   // mode2 residual base
  const int* esrc; const int* edst; const float* est;
  const u16 *w0, *w1, *w2;
  const float *b0, *b1, *b2;
  float* out;
  int s, half;
};

// MODE 0: leaf [x_in[esrc[e]], ef[e]] -> xw[edst[e]]
// MODE 1: up   [xw[esrc[s+e]], xw[esrc[s+half+e]]] -> xw[edst[s+e]]
// MODE 2: down [xw[edst[s+e]], state] -> xw[esrc[s+e]] += bottom
// Each wave: private 8KB LDS slice (SH 4KB hi, SL 4KB lo), NO barriers.
template<int MODE>
__device__ __forceinline__ void wave_tile(const WTP& p, char* SH, char* SL, int lane,
                                          int base1, int base2, int split, int nvalid) {
  const int g = lane >> 4;     // 0..3 (k-subgroup / out-row group)
  const int q = lane & 15;     // frag row / out col-within-nt
  const int aswz = (q & 7) << 4;

  auto eidx = [&](int r) {
    int rc = (r < nvalid) ? r : 0;
    if (MODE == 2) return (rc < split) ? (base1 + rc) : (base2 + (rc - split));
    return base1 + rc;
  };

  bf16x8 ah[4], al[4];
  f32x4 acc[8];

  auto initacc = [&](const float* b) {
    #pragma unroll
    for (int nt = 0; nt < 8; ++nt) { float bv = b[nt * 16 + q]; acc[nt] = (f32x4){bv, bv, bv, bv}; }
  };

  // stage one 128-wide K chunk (16 rows) from gathered f32 rows into SH/SL
  auto stage128 = [&](int c) {
    int rl = lane >> 5;        // 0..1
    int f4 = lane & 31;        // float4 index within row
    #pragma unroll
    for (int i = 0; i < 8; ++i) {
      int row = i * 2 + rl;
      int e = eidx(row);
      const float* src;
      if (MODE == 0)      src = (c == 0) ? p.gA + (size_t)p.esrc[e] * 128
                                         : p.gB + (size_t)e * 128;
      else if (MODE == 1) src = p.gA + (size_t)p.esrc[p.s + (c ? p.half + e : e)] * 128;
      else                src = p.gA + (size_t)p.edst[p.s + e] * 128;
      float4 v = *(const float4*)(src + f4 * 4);
      uint2 hw, lw; split4(v, hw, lw);
      int byt = (f4 * 8) ^ ((row & 7) << 4);
      *(uint2_a*)(SH + row * 256 + byt) = hw;
      *(uint2_a*)(SL + row * 256 + byt) = lw;
    }
  };

  auto frags = [&](int nkc) {
    #pragma unroll
    for (int kc = 0; kc < 4; ++kc) {
      if (kc < nkc) {
        int byt = (kc * 64 + g * 16) ^ aswz;
        ah[kc] = *(const bf16x8_a*)(SH + q * 256 + byt);
        al[kc] = *(const bf16x8_a*)(SL + q * 256 + byt);
      }
    }
  };

  // KCw = fragment stride of THIS weight matrix (w0: 8 or 5; w1/w2: 4)
  auto accum = [&](const u16* whi, int kcb, int nkc, int KCw) {
    const u16* wlo = whi + LO_OFF;
    #pragma unroll
    for (int nt = 0; nt < 8; ++nt) {
      #pragma unroll
      for (int kc = 0; kc < 4; ++kc) {
        if (kc < nkc) {
          size_t o = ((size_t)(nt * KCw + kcb + kc) << 9) + lane * 8;
          bf16x8 bh = *(const bf16x8*)(whi + o);
          bf16x8 bl = *(const bf16x8*)(wlo + o);
          acc[nt] = MFMA16(ah[kc], bh, acc[nt]);
          acc[nt] = MFMA16(ah[kc], bl, acc[nt]);
          acc[nt] = MFMA16(al[kc], bh, acc[nt]);
        }
      }
    }
  };

  auto writeH = [&]() {   // relu + split back to SH/SL (K=128 layout)
    #pragma unroll
    for (int nt = 0; nt < 8; ++nt) {
      int col = nt * 16 + q;
      #pragma unroll
      for (int r = 0; r < 4; ++r) {
        int row = g * 4 + r;
        float v = fmaxf(acc[nt][r], 0.f);
        int byt = (col * 2) ^ ((row & 7) << 4);
        u16 hv = f2bf(v);
        *(u16_a*)(SH + row * 256 + byt) = hv;
        *(u16_a*)(SL + row * 256 + byt) = f2bf(v - bf2f(hv));
      }
    }
  };

  // ---- layer 0 ----
  initacc(p.b0);
  stage128(0);
  LDS_FENCE();
  frags(4);
  if (MODE != 2) {
    accum(p.w0, 0, 4, 8);
    LDS_FENCE();       // WAR: keep stage(1) writes after frags(4) reads
    stage128(1);
    LDS_FENCE();
    frags(4);
    accum(p.w0, 4, 4, 8);
  } else {
    accum(p.w0, 0, 4, 5);
    LDS_FENCE();       // WAR: keep state writes after frags(4) reads
    { // state mini-chunk: k-local 0..31, state at k-local 0
      int row = lane >> 2, c4 = lane & 3;
      float sv = (c4 == 0) ? p.est[p.s + eidx(row)] : 0.f;
      uint4 hz = {0u, 0u, 0u, 0u}, lz = {0u, 0u, 0u, 0u};
      hz.x = (unsigned)f2bf(sv);
      int byt = (c4 * 16) ^ ((row & 7) << 4);
      *(uint4_a*)(SH + row * 256 + byt) = hz;
      *(uint4_a*)(SL + row * 256 + byt) = lz;
    }
    LDS_FENCE();
    frags(1);
    accum(p.w0, 4, 1, 5);
  }
  LDS_FENCE();
  writeH();
  LDS_FENCE();

  // ---- layer 1 ----
  initacc(p.b1);
  frags(4);
  accum(p.w1, 0, 4, 4);
  LDS_FENCE();
  writeH();
  LDS_FENCE();

  // ---- layer 2 + epilogue ----
  initacc(p.b2);
  frags(4);
  accum(p.w2, 0, 4, 4);
  int nodes[4];
  #pragma unroll
  for (int r = 0; r < 4; ++r) {
    int rr = g * 4 + r;
    bool v = rr < nvalid;
    int e = eidx(rr);
    int nd = -1;
    if (v) nd = (MODE == 0) ? p.edst[e] : ((MODE == 1) ? p.edst[p.s + e] : p.esrc[p.s + e]);
    nodes[r] = nd;
  }
  #pragma unroll
  for (int nt = 0; nt < 8; ++nt) {
    int col = nt * 16 + q;
    #pragma unroll
    for (int r = 0; r < 4; ++r) {
      if (nodes[r] >= 0) {
        float v = acc[nt][r];
        if (MODE == 2) v += p.addb[(size_t)nodes[r] * 128 + col];
        p.out[(size_t)nodes[r] * 128 + col] = v;
      }
    }
  }
}

// ---------------- big-level kernel: 4 independent waves, 4 tiles/block ----------------
template<int MODE>
__global__ __launch_bounds__(256, 3) void level_kernel(WTP p, int rows) {
  __shared__ char LB[32768];
  int wv = threadIdx.x >> 6, lane = threadIdx.x & 63;
  char* SH = LB + wv * 8192;
  char* SL = SH + 4096;
  int t16 = (blockIdx.x * 4 + wv) * 16;
  if (t16 >= rows) return;
  int nv = rows - t16; if (nv > 16) nv = 16;
  wave_tile<MODE>(p, SH, SL, lane, t16, 0, 16, nv);
}

// ---------------- fused tiny levels: 1 block per tree, block-local sync only ----------------
struct FGP {
  WTP g;   // mg (mode 1) params, s/half patched per level
  WTP r;   // mr (mode 2) params
  int nlev;
  int mode[17], s[17], half[17], m[17];
};

__global__ __launch_bounds__(256, 3) void tiny_fused(FGP fp) {
  __shared__ char LB[32768];
  int wv = threadIdx.x >> 6, lane = threadIdx.x & 63;
  char* SH = LB + wv * 8192;
  char* SL = SH + 4096;
  int b = blockIdx.x;   // tree 0..7
  for (int li = 0; li < fp.nlev; ++li) {
    if (fp.mode[li] == 1) {
      int half = fp.half[li];          // total rows (all trees)
      int rt = half >> 3;              // rows per tree (tree-major contiguous)
      int tiles = (rt + 15) >> 4;
      WTP p = fp.g; p.s = fp.s[li]; p.half = half;
      for (int t = wv; t < tiles; t += 4) {
        int r0 = t * 16;
        int nv = rt - r0; if (nv > 16) nv = 16;
        wave_tile<1>(p, SH, SL, lane, b * rt + r0, 0, 16, nv);
      }
    } else {
      int m = fp.m[li];
      int hs = m >> 4;                 // per-tree left-half edge count
      int rt = m >> 3;                 // rows per tree (left chunk + right chunk)
      int tiles = (rt + 15) >> 4;
      WTP p = fp.r; p.s = fp.s[li]; p.half = 0;
      for (int t = wv; t < tiles; t += 4) {
        int r0 = t * 16;
        int nv = rt - r0; if (nv > 16) nv = 16;
        int b1, b2, sp;
        if (r0 + 16 <= hs)      { b1 = b * hs + r0;                     b2 = 0; sp = 16; }
        else if (r0 >= hs)      { b1 = (m >> 1) + b * hs + (r0 - hs);   b2 = 0; sp = 16; }
        else                    { b1 = b * hs + r0; b2 = (m >> 1) + b * hs; sp = hs - r0; }
        wave_tile<2>(p, SH, SL, lane, b1, b2, sp, nv);
      }
    }
    __threadfence_block();
    __syncthreads();
  }
}

extern "C" void kernel_launch(void* const* d_in, const int* in_sizes, int n_in,
                              void* d_out, int out_size, void* d_ws, size_t ws_size,
                              hipStream_t stream) {
  const float* xin  = (const float*)d_in[0];
  const int*   esrc = (const int*)d_in[1];
  const int*   edst = (const int*)d_in[2];
  const float* est  = (const float*)d_in[3];
  const float* ef   = (const float*)d_in[4];
  u16* wsb = (u16*)d_ws;
  float* xw = (float*)d_out;

  // ---- weight prep ----
  PrepP pp;
  const int widx[9] = {6, 8, 10, 12, 14, 16, 18, 20, 22};
  for (int i = 0; i < 9; ++i) pp.w[i] = (const float*)d_in[widx[i]];
  pp.out = wsb;
  prep_kernel<<<dim3(720), dim3(256), 0, stream>>>(pp);

  // edge-block geometry (B=8, D=14, N_LEAF=8192 -> nL=65536)
  int blk[14], off[14];
  blk[0] = 65536; off[0] = 0;
  for (int d = 1; d <= 13; ++d) { blk[d] = 65536 >> (d - 1); off[d] = off[d - 1] + blk[d - 1]; }

  WTP nem;
  nem.gA = xin; nem.gB = ef; nem.addb = nullptr;
  nem.esrc = esrc; nem.edst = edst; nem.est = est;
  nem.w0 = wsb + 0; nem.w1 = wsb + 32768; nem.w2 = wsb + 49152;
  nem.b0 = (const float*)d_in[7]; nem.b1 = (const float*)d_in[9]; nem.b2 = (const float*)d_in[11];
  nem.out = xw; nem.s = 0; nem.half = 0;

  WTP mg = nem;
  mg.gA = xw; mg.gB = nullptr;
  mg.w0 = wsb + 65536; mg.w1 = wsb + 98304; mg.w2 = wsb + 114688;
  mg.b0 = (const float*)d_in[13]; mg.b1 = (const float*)d_in[15]; mg.b2 = (const float*)d_in[17];

  WTP mr = nem;
  mr.gA = xw; mr.addb = xw;
  mr.w0 = wsb + 131072; mr.w1 = wsb + 151552; mr.w2 = wsb + 167936;
  mr.b0 = (const float*)d_in[19]; mr.b1 = (const float*)d_in[21]; mr.b2 = (const float*)d_in[23];

  // phase 1: leaf embed (65536 rows)
  level_kernel<0><<<dim3(1024), dim3(256), 0, stream>>>(nem, 65536);

  // phase 2: upward merge, big levels d=1..4
  for (int d = 1; d <= 4; ++d) {
    int rows = blk[d] / 2;
    WTP p = mg; p.s = off[d]; p.half = rows;
    level_kernel<1><<<dim3((rows + 63) / 64), dim3(256), 0, stream>>>(p, rows);
  }

  // fused tiny levels: up d=5..13, down bi=13..6 — 1 block per tree
  {
    FGP fp;
    fp.g = mg; fp.r = mr;
    int li = 0;
    for (int d = 5; d <= 13; ++d) { fp.mode[li] = 1; fp.s[li] = off[d]; fp.half[li] = blk[d] / 2; fp.m[li] = 0; ++li; }
    for (int bi = 13; bi >= 6; --bi) { fp.mode[li] = 2; fp.s[li] = off[bi]; fp.half[li] = 0; fp.m[li] = blk[bi]; ++li; }
    fp.nlev = li;   // 17
    tiny_fused<<<dim3(8), dim3(256), 0, stream>>>(fp);
  }

  // phase 3: downward, big levels bi=5..0
  for (int bi = 5; bi >= 0; --bi) {
    int rows = blk[bi];
    WTP p = mr; p.s = off[bi];
    p.addb = (bi == 0) ? xin : xw;
    level_kernel<2><<<dim3((rows + 63) / 64), dim3(256), 0, stream>>>(p, rows);
  }
}

// Round 7
// 951.160 us; speedup vs baseline: 2.3282x; 2.3282x over previous
//
#include <hip/hip_runtime.h>
#include <cstdint>
#include <cstddef>

typedef __attribute__((ext_vector_type(8))) short bf16x8;
typedef bf16x8 __attribute__((may_alias)) bf16x8_a;
typedef __attribute__((ext_vector_type(4))) float f32x4;
typedef unsigned short u16;
typedef u16 __attribute__((may_alias)) u16_a;
typedef uint2 __attribute__((may_alias)) uint2_a;
typedef uint4 __attribute__((may_alias)) uint4_a;

#define LO_OFF 184320
#define MFMA16(a,b,c) __builtin_amdgcn_mfma_f32_16x16x32_bf16((a),(b),(c),0,0,0)

__device__ __forceinline__ u16 f2bf(float f) {
  union { float f; unsigned u; } c; c.f = f;
  unsigned u = c.u + 0x7fffu + ((c.u >> 16) & 1u);
  return (u16)(u >> 16);
}
__device__ __forceinline__ float bf2f(u16 h) {
  union { unsigned u; float f; } c; c.u = ((unsigned)h) << 16;
  return c.f;
}

// ---------------- weight prep: fp32 [K][128] -> frag-linear split-bf16 ----------------
// frag fc = nt*KC + kc; elem (fc*64 + lane)*8 + j <-> n = nt*16 + (lane&15),
// k = kc*32 + (lane>>4)*8 + j (zero-padded past K)
struct PrepP { const float* w[9]; u16* out; };

__global__ __launch_bounds__(256) void prep_kernel(PrepP pp) {
  int gid = blockIdx.x * 256 + threadIdx.x;
  if (gid >= LO_OFF) return;
  const int Ks[9]  = {256,128,128, 256,128,128, 129,128,128};
  const int szs[9] = {32768,16384,16384, 32768,16384,16384, 20480,16384,16384};
  const int KCs[9] = {8,4,4, 8,4,4, 5,4,4};
  int m = 0, off = gid;
  while (m < 8 && off >= szs[m]) { off -= szs[m]; ++m; }
  int j    = off & 7;
  int t    = off >> 3;
  int lane = t & 63;
  int fc   = t >> 6;
  int KC   = KCs[m];
  int kc   = fc % KC;
  int nt   = fc / KC;
  int n = nt * 16 + (lane & 15);
  int k = kc * 32 + (lane >> 4) * 8 + j;
  float v = 0.f;
  if (k < Ks[m]) v = pp.w[m][(size_t)k * 128 + n];
  u16 hi = f2bf(v);
  u16 lo = f2bf(v - bf2f(hi));
  pp.out[gid] = hi;
  pp.out[LO_OFF + gid] = lo;
}

// ---------------- cooperative 16-row tile (256 threads, 4 waves split 8 nt) ----------------
struct WTP {
  const float* gA; const float* gB; const float* addb;
  const int* esrc; const int* edst; const float* est;
  const u16 *w0, *w1, *w2;
  const float *b0, *b1, *b2;
  float* out;
  int s, half;
};

// A rows in LDS: [16][256] u16 (512B/row), two 256B halves ping-pong between layers.
// element (row, kk) at half base hb: byte hb + ((kk*2 & ~15) ^ ((row&7)<<4)) + (kk*2 & 14)
__device__ __forceinline__ void load_frags(const u16* SH, const u16* SL, int rbase, int lane,
                                           bf16x8* ah, bf16x8* al) {
  int arow = lane & 15, g = lane >> 4, aswz = (arow & 7) << 4;
  const char* shb = (const char*)SH + arow * 512 + rbase;
  const char* slb = (const char*)SL + arow * 512 + rbase;
  #pragma unroll
  for (int kc = 0; kc < 4; ++kc) {
    int byt = (kc * 64 + g * 16) ^ aswz;
    ah[kc] = *(const bf16x8_a*)(shb + byt);
    al[kc] = *(const bf16x8_a*)(slb + byt);
  }
}

__device__ __forceinline__ void accum2(f32x4& a0, f32x4& a1, const bf16x8* ah, const bf16x8* al,
                                       const u16* wgt, int nt0, int KCw, int kcb, int nkc, int lane) {
  #pragma unroll
  for (int kc = 0; kc < 4; ++kc) {
    if (kc < nkc) {
      const u16* wb0 = wgt + (((size_t)(nt0 * KCw + kcb + kc)) << 9) + lane * 8;
      const u16* wb1 = wb0 + ((size_t)KCw << 9);
      bf16x8 bh0 = *(const bf16x8*)wb0;
      bf16x8 bl0 = *(const bf16x8*)(wb0 + LO_OFF);
      bf16x8 bh1 = *(const bf16x8*)wb1;
      bf16x8 bl1 = *(const bf16x8*)(wb1 + LO_OFF);
      a0 = MFMA16(ah[kc], bh0, a0); a1 = MFMA16(ah[kc], bh1, a1);
      a0 = MFMA16(ah[kc], bl0, a0); a1 = MFMA16(ah[kc], bl1, a1);
      a0 = MFMA16(al[kc], bh0, a0); a1 = MFMA16(al[kc], bh1, a1);
    }
  }
}

// relu + split-bf16 write of this wave's 2-nt col slice for all 16 rows, to half obase
__device__ __forceinline__ void writeH(u16* SH, u16* SL, int obase, int lane, int nt0,
                                       f32x4 a0, f32x4 a1) {
  int arow = lane & 15, g = lane >> 4;
  int c0 = (nt0 * 16 + arow) * 2, c1 = c0 + 32;
  #pragma unroll
  for (int r = 0; r < 4; ++r) {
    int row = g * 4 + r;
    int oswz = (row & 7) << 4;
    char* sh = (char*)SH + row * 512 + obase;
    char* sl = (char*)SL + row * 512 + obase;
    float v0 = fmaxf(a0[r], 0.f), v1 = fmaxf(a1[r], 0.f);
    u16 h0 = f2bf(v0), h1 = f2bf(v1);
    *(u16_a*)(sh + (c0 ^ oswz)) = h0; *(u16_a*)(sl + (c0 ^ oswz)) = f2bf(v0 - bf2f(h0));
    *(u16_a*)(sh + (c1 ^ oswz)) = h1; *(u16_a*)(sl + (c1 ^ oswz)) = f2bf(v1 - bf2f(h1));
  }
}

// MODE 0: leaf [x_in[esrc[e]], ef[e]] -> xw[edst[e]]
// MODE 1: up   [xw[esrc[s+e]], xw[esrc[s+half+e]]] -> xw[edst[s+e]]
// MODE 2: down [xw[edst[s+e]], state] -> xw[esrc[s+e]] += addb[esrc[s+e]]
template<int MODE>
__device__ __forceinline__ void coop_tile(const WTP& p, int tid, u16* SH, u16* SL,
                                          int base1, int base2, int split, int nvalid, bool active) {
  const int lane = tid & 63, wv = tid >> 6;
  const int arow = lane & 15;
  const int nt0 = wv * 2;

  auto eidx = [&](int r) -> int {
    int rc = (r < nvalid) ? r : 0;
    if (MODE == 2) return (rc < split) ? (base1 + rc) : (base2 + (rc - split));
    return base1 + rc;
  };

  f32x4 a0, a1;
  bf16x8 ah[4], al[4];
  const int srow = tid >> 4, sq = tid & 15;           // stage: thread -> (row, col-slot)
  const int sswz = (srow & 7) << 4;
  char* ssh = (char*)SH + srow * 512;
  char* ssl = (char*)SL + srow * 512;
  bool sok = srow < nvalid;
  int se = eidx(srow);

  auto stage_chunk = [&](const float* src, int cbase) {   // 128 floats of row srow
    #pragma unroll
    for (int i = 0; i < 2; ++i) {
      int f4l = sq * 2 + i;
      float4 v = {0.f, 0.f, 0.f, 0.f};
      if (sok) v = *(const float4*)(src + f4l * 4);
      u16 h0 = f2bf(v.x), h1 = f2bf(v.y), h2 = f2bf(v.z), h3 = f2bf(v.w);
      uint2 hw, lw;
      hw.x = (unsigned)h0 | ((unsigned)h1 << 16);
      hw.y = (unsigned)h2 | ((unsigned)h3 << 16);
      lw.x = (unsigned)f2bf(v.x - bf2f(h0)) | ((unsigned)f2bf(v.y - bf2f(h1)) << 16);
      lw.y = (unsigned)f2bf(v.z - bf2f(h2)) | ((unsigned)f2bf(v.w - bf2f(h3)) << 16);
      int byt = cbase + ((f4l * 8) ^ sswz);
      *(uint2_a*)(ssh + byt) = hw;
      *(uint2_a*)(ssl + byt) = lw;
    }
  };

  // ---- stage chunk 0 (+ state chunk for MODE 2) ----
  if (active) {
    if (MODE == 0)      stage_chunk(p.gA + (size_t)p.esrc[se] * 128, 0);
    else if (MODE == 1) stage_chunk(p.gA + (size_t)p.esrc[p.s + se] * 128, 0);
    else {
      stage_chunk(p.gA + (size_t)p.edst[p.s + se] * 128, 0);
      if (sq < 4) {  // k-chunk 4 (bytes 256..319): state at k=128, zeros after
        float sv = (sq == 0 && sok) ? p.est[p.s + se] : 0.f;
        uint4 hz = {0u,0u,0u,0u}, lz = {0u,0u,0u,0u};
        hz.x = (unsigned)f2bf(sv);
        int byt = 256 + ((sq * 16) ^ sswz);
        *(uint4_a*)(ssh + byt) = hz;
        *(uint4_a*)(ssl + byt) = lz;
      }
    }
  }
  __syncthreads();                                       // S1

  // ---- layer 0 ----
  {
    float bv0 = p.b0[nt0 * 16 + arow], bv1 = p.b0[nt0 * 16 + 16 + arow];
    a0 = (f32x4){bv0,bv0,bv0,bv0}; a1 = (f32x4){bv1,bv1,bv1,bv1};
  }
  if (MODE != 2) {
    if (active) {
      load_frags(SH, SL, 0, lane, ah, al);
      accum2(a0, a1, ah, al, p.w0, nt0, 8, 0, 4, lane);
      // stage chunk 1 (bytes 256..511) — disjoint from pass-1 reads (0..255)
      const float* src2 = (MODE == 0) ? p.gB + (size_t)se * 128
                                      : p.gA + (size_t)p.esrc[p.s + p.half + se] * 128;
      stage_chunk(src2, 256);
    }
    __syncthreads();                                     // S2
    if (active) {
      load_frags(SH, SL, 256, lane, ah, al);
      accum2(a0, a1, ah, al, p.w0, nt0, 8, 4, 4, lane);
    }
  } else {
    if (active) {
      load_frags(SH, SL, 0, lane, ah, al);
      accum2(a0, a1, ah, al, p.w0, nt0, 5, 0, 4, lane);
      {  // frag chunk 4 (state)
        int g = lane >> 4, aswz = (arow & 7) << 4;
        int byt = 256 + ((g * 16) ^ aswz);
        ah[0] = *(const bf16x8_a*)((const char*)SH + arow * 512 + byt);
        al[0] = *(const bf16x8_a*)((const char*)SL + arow * 512 + byt);
      }
      accum2(a0, a1, ah, al, p.w0, nt0, 5, 4, 1, lane);
    }
  }
  __syncthreads();                                       // S3 (all reads of 256..511 done)
  if (active) writeH(SH, SL, 256, lane, nt0, a0, a1);    // L0 out -> half 1
  __syncthreads();                                       // S4

  // ---- layer 1: read half 1, write half 0 ----
  {
    float bv0 = p.b1[nt0 * 16 + arow], bv1 = p.b1[nt0 * 16 + 16 + arow];
    a0 = (f32x4){bv0,bv0,bv0,bv0}; a1 = (f32x4){bv1,bv1,bv1,bv1};
  }
  if (active) {
    load_frags(SH, SL, 256, lane, ah, al);
    accum2(a0, a1, ah, al, p.w1, nt0, 4, 0, 4, lane);
    writeH(SH, SL, 0, lane, nt0, a0, a1);                // disjoint from reads (256..511)
  }
  __syncthreads();                                       // S5

  // ---- layer 2: read half 0, scatter to global ----
  {
    float bv0 = p.b2[nt0 * 16 + arow], bv1 = p.b2[nt0 * 16 + 16 + arow];
    a0 = (f32x4){bv0,bv0,bv0,bv0}; a1 = (f32x4){bv1,bv1,bv1,bv1};
  }
  if (active) {
    load_frags(SH, SL, 0, lane, ah, al);
    accum2(a0, a1, ah, al, p.w2, nt0, 4, 0, 4, lane);
    int g = lane >> 4;
    int col0 = nt0 * 16 + arow, col1 = col0 + 16;
    #pragma unroll
    for (int r = 0; r < 4; ++r) {
      int rr = g * 4 + r;
      if (rr < nvalid) {
        int e = eidx(rr);
        int nd = (MODE == 0) ? p.edst[e] : ((MODE == 1) ? p.edst[p.s + e] : p.esrc[p.s + e]);
        size_t bo = (size_t)nd * 128;
        float v0 = a0[r], v1 = a1[r];
        if (MODE == 2) { v0 += p.addb[bo + col0]; v1 += p.addb[bo + col1]; }
        p.out[bo + col0] = v0;
        p.out[bo + col1] = v1;
      }
    }
  }
}

// ---------------- big-level kernel: one 16-row tile per 256-thread block ----------------
template<int MODE>
__global__ __launch_bounds__(256, 4) void level_kernel(WTP p, int rows) {
  __shared__ u16 SH[16 * 256];
  __shared__ u16 SL[16 * 256];
  int base1 = blockIdx.x * 16;
  int nv = rows - base1; if (nv > 16) nv = 16;
  coop_tile<MODE>(p, threadIdx.x, SH, SL, base1, 0, 16, nv, true);
}

// ---------------- fused tiny levels: 1 block/tree, 4 tile-groups, lockstep rounds ----------------
struct FGP {
  WTP g;   // mg (mode 1)
  WTP r;   // mr (mode 2)
  int nlev;
  int mode[17], s[17], half[17], m[17];
};

__global__ __launch_bounds__(1024) void tiny_fused(FGP fp) {
  __shared__ u16 SH[4][16 * 256];
  __shared__ u16 SL[4][16 * 256];
  const int grp = threadIdx.x >> 8;
  const int tid = threadIdx.x & 255;
  const int b = blockIdx.x;   // tree 0..7
  for (int li = 0; li < fp.nlev; ++li) {
    if (fp.mode[li] == 1) {
      int half = fp.half[li];
      int rt = half >> 3;                    // rows per tree
      int tiles = (rt + 15) >> 4;
      int rounds = (tiles + 3) >> 2;
      WTP p = fp.g; p.s = fp.s[li]; p.half = half;
      for (int rnd = 0; rnd < rounds; ++rnd) {
        int t = rnd * 4 + grp;
        bool active = t < tiles;
        int tc = active ? t : 0;
        int r0 = tc * 16;
        int nv = rt - r0; if (nv > 16) nv = 16;
        coop_tile<1>(p, tid, SH[grp], SL[grp], b * rt + r0, 0, 16, nv, active);
      }
    } else {
      int m = fp.m[li];
      int hs = m >> 4;                       // per-tree left-edge count
      int rt = m >> 3;
      int tiles = (rt + 15) >> 4;
      int rounds = (tiles + 3) >> 2;
      WTP p = fp.r; p.s = fp.s[li]; p.half = 0;
      for (int rnd = 0; rnd < rounds; ++rnd) {
        int t = rnd * 4 + grp;
        bool active = t < tiles;
        int tc = active ? t : 0;
        int r0 = tc * 16;
        int nv = rt - r0; if (nv > 16) nv = 16;
        int b1, b2, sp;
        if (r0 + 16 <= hs)      { b1 = b * hs + r0;                   b2 = 0;                     sp = 16; }
        else if (r0 >= hs)      { b1 = (m >> 1) + b * hs + (r0 - hs); b2 = 0;                     sp = 16; }
        else                    { b1 = b * hs + r0;                   b2 = (m >> 1) + b * hs;     sp = hs - r0; }
        coop_tile<2>(p, tid, SH[grp], SL[grp], b1, b2, sp, nv, active);
      }
    }
    __threadfence_block();
    __syncthreads();   // level boundary: xw writes visible to next level's reads
  }
}

extern "C" void kernel_launch(void* const* d_in, const int* in_sizes, int n_in,
                              void* d_out, int out_size, void* d_ws, size_t ws_size,
                              hipStream_t stream) {
  const float* xin  = (const float*)d_in[0];
  const int*   esrc = (const int*)d_in[1];
  const int*   edst = (const int*)d_in[2];
  const float* est  = (const float*)d_in[3];
  const float* ef   = (const float*)d_in[4];
  u16* wsb = (u16*)d_ws;
  float* xw = (float*)d_out;

  // ---- weight prep ----
  PrepP pp;
  const int widx[9] = {6, 8, 10, 12, 14, 16, 18, 20, 22};
  for (int i = 0; i < 9; ++i) pp.w[i] = (const float*)d_in[widx[i]];
  pp.out = wsb;
  prep_kernel<<<dim3(720), dim3(256), 0, stream>>>(pp);

  // edge-block geometry (B=8, D=14, N_LEAF=8192 -> nL=65536)
  int blk[14], off[14];
  blk[0] = 65536; off[0] = 0;
  for (int d = 1; d <= 13; ++d) { blk[d] = 65536 >> (d - 1); off[d] = off[d - 1] + blk[d - 1]; }

  WTP nem;
  nem.gA = xin; nem.gB = ef; nem.addb = nullptr;
  nem.esrc = esrc; nem.edst = edst; nem.est = est;
  nem.w0 = wsb + 0; nem.w1 = wsb + 32768; nem.w2 = wsb + 49152;
  nem.b0 = (const float*)d_in[7]; nem.b1 = (const float*)d_in[9]; nem.b2 = (const float*)d_in[11];
  nem.out = xw; nem.s = 0; nem.half = 0;

  WTP mg = nem;
  mg.gA = xw; mg.gB = nullptr;
  mg.w0 = wsb + 65536; mg.w1 = wsb + 98304; mg.w2 = wsb + 114688;
  mg.b0 = (const float*)d_in[13]; mg.b1 = (const float*)d_in[15]; mg.b2 = (const float*)d_in[17];

  WTP mr = nem;
  mr.gA = xw; mr.addb = xw;
  mr.w0 = wsb + 131072; mr.w1 = wsb + 151552; mr.w2 = wsb + 167936;
  mr.b0 = (const float*)d_in[19]; mr.b1 = (const float*)d_in[21]; mr.b2 = (const float*)d_in[23];

  // phase 1: leaf embed (65536 rows)
  level_kernel<0><<<dim3(4096), dim3(256), 0, stream>>>(nem, 65536);

  // phase 2: upward merge, big levels d=1..4
  for (int d = 1; d <= 4; ++d) {
    int rows = blk[d] / 2;
    WTP p = mg; p.s = off[d]; p.half = rows;
    level_kernel<1><<<dim3((rows + 15) / 16), dim3(256), 0, stream>>>(p, rows);
  }

  // fused tiny levels: up d=5..13, down bi=13..6 — 1 block/tree, 1024 threads
  {
    FGP fp;
    fp.g = mg; fp.r = mr;
    int li = 0;
    for (int d = 5; d <= 13; ++d) { fp.mode[li] = 1; fp.s[li] = off[d]; fp.half[li] = blk[d] / 2; fp.m[li] = 0; ++li; }
    for (int bi = 13; bi >= 6; --bi) { fp.mode[li] = 2; fp.s[li] = off[bi]; fp.half[li] = 0; fp.m[li] = blk[bi]; ++li; }
    fp.nlev = li;   // 17
    tiny_fused<<<dim3(8), dim3(1024), 0, stream>>>(fp);
  }

  // phase 3: downward, big levels bi=5..0
  for (int bi = 5; bi >= 0; --bi) {
    int rows = blk[bi];
    WTP p = mr; p.s = off[bi];
    p.addb = (bi == 0) ? xin : xw;
    level_kernel<2><<<dim3((rows + 15) / 16), dim3(256), 0, stream>>>(p, rows);
  }
}